// Round 1
// 318.395 us; speedup vs baseline: 1.0478x; 1.0478x over previous
//
#include <hip/hip_runtime.h>
#include <math.h>

#define GAMMA_ 0.99f
#define GL_ (0.99f * 0.95f)
#define L_ 32            // chunk length (mask fits in u32)

typedef float    f2 __attribute__((ext_vector_type(2)));
typedef int      i2 __attribute__((ext_vector_type(2)));
typedef unsigned u2 __attribute__((ext_vector_type(2)));

// ---------------------------------------------------------------------------
// Pass 1: per (chunk, column-pair) reverse scan with zero carry, 2 columns
// per thread via float2 (8 B/lane). Grid = (N/2/256, C) = 1024 blocks ->
// 16 waves/CU (2x the float4 version) for latency hiding. Emits per-chunk
// affine summary (A,B), stats (Sa,Sa2,SaP,SP,SP2), and a nonterminal bitmask.
// dones is read exactly once per bench iteration -> nontemporal load keeps
// LLC space for rewards/values which are re-read by pass3.
// ---------------------------------------------------------------------------
__global__ __launch_bounds__(256)
void gae_pass1(const f2* __restrict__ rw, const f2* __restrict__ vv,
               const i2* __restrict__ dn,
               f2* __restrict__ A, f2* __restrict__ B,
               f2* __restrict__ Sa, f2* __restrict__ Sa2,
               f2* __restrict__ SaP, f2* __restrict__ SP,
               f2* __restrict__ SP2, u2* __restrict__ mask,
               int T, int N2)
{
    int q = blockIdx.x * blockDim.x + threadIdx.x;   // column-pair index
    int chunk = blockIdx.y;
    if (q >= N2) return;
    int s = chunk * L_;
    int e = s + L_; if (e > T) e = T;

    float a[2]  = {0.f,0.f}, P[2]   = {1.f,1.f};
    float sa[2] = {0.f,0.f}, sa2[2] = {0.f,0.f};
    float saP[2]= {0.f,0.f}, sP[2]  = {0.f,0.f}, sP2[2] = {0.f,0.f};
    unsigned mm[2] = {0u,0u};

    f2 vn = vv[(size_t)e * N2 + q];
    float vnext[2] = {vn.x, vn.y};

    #pragma unroll 4
    for (int t = e - 1; t >= s; --t) {
        size_t off = (size_t)t * N2 + q;
        f2 r2 = rw[off];
        i2 d2 = __builtin_nontemporal_load(&dn[off]);
        f2 v2 = vv[off];
        unsigned bit = 1u << (t - s);
        #pragma unroll
        for (int j = 0; j < 2; ++j) {
            float nt = (d2[j] == 0) ? 1.0f : 0.0f;
            float delta = r2[j] + GAMMA_ * vnext[j] * nt - v2[j];
            float c = GL_ * nt;
            a[j] = delta + c * a[j];
            P[j] = c * P[j];
            sa[j]  += a[j];
            sa2[j] += a[j] * a[j];
            saP[j] += a[j] * P[j];
            sP[j]  += P[j];
            sP2[j] += P[j] * P[j];
            mm[j] |= (d2[j] == 0) ? bit : 0u;
            vnext[j] = v2[j];
        }
    }
    size_t idx = (size_t)chunk * N2 + q;
    f2 o;
    o.x = a[0];   o.y = a[1];   A[idx]   = o;
    o.x = P[0];   o.y = P[1];   B[idx]   = o;
    o.x = sa[0];  o.y = sa[1];  Sa[idx]  = o;
    o.x = sa2[0]; o.y = sa2[1]; Sa2[idx] = o;
    o.x = saP[0]; o.y = saP[1]; SaP[idx] = o;
    o.x = sP[0];  o.y = sP[1];  SP[idx]  = o;
    o.x = sP2[0]; o.y = sP2[1]; SP2[idx] = o;
    u2 om; om.x = mm[0]; om.y = mm[1];
    mask[idx] = om;
}

// ---------------------------------------------------------------------------
// Pass 2 (wave-scan): one wave per column, lane l owns chunk l (C <= 64).
// The chunk-carry recurrence g = A + B*g is an affine-map suffix scan:
// compose maps in log2(64)=6 shuffle steps, then carry[l] = A of h_{l+1}.
// 8192 waves instead of 128 -> the whole pass is a few microseconds.
// Stats reduced per-wave (shfl butterfly) then per-block (LDS) -> 512
// atomic pairs total.
// ---------------------------------------------------------------------------
__global__ __launch_bounds__(1024)
void gae_pass2_ws(const float* __restrict__ A, const float* __restrict__ B,
                  const float* __restrict__ Sa, const float* __restrict__ Sa2,
                  const float* __restrict__ SaP, const float* __restrict__ SP,
                  const float* __restrict__ SP2,
                  float* __restrict__ carry, double* __restrict__ sums,
                  int N, int C)
{
    __shared__ double psum[16], psq[16];
    int wid  = threadIdx.x >> 6;
    int lane = threadIdx.x & 63;
    int nwav = blockDim.x >> 6;
    int n = blockIdx.x * nwav + wid;           // column

    // identity map + zero stats for padding lanes
    float Ah = 0.f, Bh = 1.f;
    float sa = 0.f, sa2 = 0.f, saP = 0.f, sp = 0.f, sp2 = 0.f;
    bool act = (n < N) && (lane < C);
    size_t idx = (size_t)lane * N + n;
    if (act) {
        Ah = A[idx];  Bh = B[idx];
        sa = Sa[idx]; sa2 = Sa2[idx]; saP = SaP[idx];
        sp = SP[idx]; sp2 = SP2[idx];
    }

    // inclusive suffix scan of affine maps: h_l = f_l o f_{l+1} o ... o f_{63}
    #pragma unroll
    for (int d = 1; d < 64; d <<= 1) {
        float Ad = __shfl_down(Ah, d, 64);
        float Bd = __shfl_down(Bh, d, 64);
        if (lane + d < 64) { Ah = fmaf(Bh, Ad, Ah); Bh *= Bd; }
    }
    // carry entering chunk l = h_{l+1}(0) = A-part of lane l+1
    float e = __shfl_down(Ah, 1, 64);
    if (lane == 63) e = 0.f;

    double lsum = 0.0, lsq = 0.0;
    if (act) {
        carry[idx] = e;
        lsum = (double)(sa + sp * e);
        lsq  = (double)(sa2 + 2.0f * e * saP + (e * e) * sp2);
    }
    // wave64 butterfly
    for (int off = 32; off > 0; off >>= 1) {
        lsum += __shfl_down(lsum, off, 64);
        lsq  += __shfl_down(lsq, off, 64);
    }
    if (lane == 0) { psum[wid] = lsum; psq[wid] = lsq; }
    __syncthreads();
    if (threadIdx.x == 0) {
        double s = 0.0, s2 = 0.0;
        for (int w = 0; w < nwav; ++w) { s += psum[w]; s2 += psq[w]; }
        atomicAdd(&sums[0], s);
        atomicAdd(&sums[1], s2);
    }
}

// Fallback sequential pass2 for C > 64 (not hit at T=2048, kept for safety).
__global__ __launch_bounds__(64)
void gae_pass2_seq(const float* __restrict__ A, const float* __restrict__ B,
                   const float* __restrict__ Sa, const float* __restrict__ Sa2,
                   const float* __restrict__ SaP, const float* __restrict__ SP,
                   const float* __restrict__ SP2,
                   float* __restrict__ carry, double* __restrict__ sums,
                   int N, int C)
{
    int n = blockIdx.x * blockDim.x + threadIdx.x;
    double lsum = 0.0, lsq = 0.0;
    if (n < N) {
        float g = 0.f;
        for (int i = C - 1; i >= 0; --i) {
            int idx = i * N + n;
            carry[idx] = g;
            float e = g;
            lsum += (double)(Sa[idx] + SP[idx] * e);
            lsq  += (double)(Sa2[idx] + 2.0f * e * SaP[idx] + (e * e) * SP2[idx]);
            g = A[idx] + B[idx] * g;
        }
    }
    for (int off = 32; off > 0; off >>= 1) {
        lsum += __shfl_down(lsum, off, 64);
        lsq  += __shfl_down(lsq, off, 64);
    }
    if ((threadIdx.x & 63) == 0) {
        atomicAdd(&sums[0], lsum);
        atomicAdd(&sums[1], lsq);
    }
}

// ---------------------------------------------------------------------------
// Pass 3: redo the scan seeded with the true carry; normalize and emit.
// 2 columns/thread (same 16 waves/CU geometry as pass1). Outputs are
// write-once -> nontemporal stores keep rw/vv resident in LLC.
// ---------------------------------------------------------------------------
__global__ __launch_bounds__(256)
void gae_pass3(const f2* __restrict__ rw, const f2* __restrict__ vv,
               const u2* __restrict__ mask, const f2* __restrict__ carry,
               const double* __restrict__ sums,
               f2* __restrict__ out_adv, f2* __restrict__ out_ret,
               int T, int N2, double Minv, double Mm1inv)
{
    int q = blockIdx.x * blockDim.x + threadIdx.x;
    int chunk = blockIdx.y;
    if (q >= N2) return;
    int s = chunk * L_;
    int e = s + L_; if (e > T) e = T;

    double S = sums[0], S2 = sums[1];
    float mean = (float)(S * Minv);
    double vard = (S2 - S * S * Minv) * Mm1inv;
    float inv = (float)(1.0 / (sqrt(vard) + 1e-8));

    size_t idx = (size_t)chunk * N2 + q;
    f2 c2 = carry[idx];
    u2 m2 = mask[idx];
    float a[2] = {c2.x, c2.y};
    unsigned mm[2] = {m2.x, m2.y};

    f2 vn = vv[(size_t)e * N2 + q];
    float vnext[2] = {vn.x, vn.y};

    #pragma unroll 4
    for (int t = e - 1; t >= s; --t) {
        size_t off = (size_t)t * N2 + q;
        f2 r2 = rw[off];
        f2 v2 = vv[off];
        unsigned bit = 1u << (t - s);
        f2 oa, orr;
        #pragma unroll
        for (int j = 0; j < 2; ++j) {
            float nt = (mm[j] & bit) ? 1.0f : 0.0f;
            float delta = r2[j] + GAMMA_ * vnext[j] * nt - v2[j];
            a[j] = delta + GL_ * nt * a[j];
            oa[j]  = (a[j] - mean) * inv;
            orr[j] = a[j] + v2[j];
            vnext[j] = v2[j];
        }
        __builtin_nontemporal_store(oa,  &out_adv[off]);
        __builtin_nontemporal_store(orr, &out_ret[off]);
    }
}

extern "C" void kernel_launch(void* const* d_in, const int* in_sizes, int n_in,
                              void* d_out, int out_size, void* d_ws, size_t ws_size,
                              hipStream_t stream)
{
    const float* rw = (const float*)d_in[0];
    const float* vv = (const float*)d_in[1];
    const int*   dn = (const int*)d_in[2];

    long long TN = in_sizes[0];          // T*N
    long long VN = in_sizes[1];          // (T+1)*N
    int N = (int)(VN - TN);
    int T = (int)(TN / N);
    int N2 = N / 2;
    int C = (T + L_ - 1) / L_;           // 64 for T=2048

    // Workspace: [2 doubles][mask: C*N u32][8 float arrays of C*N]
    char* ws = (char*)d_ws;
    double* sums = (double*)ws;
    size_t cn = (size_t)C * N;
    unsigned* mask = (unsigned*)(ws + 16);
    float* f   = (float*)(ws + 16 + cn * 4);
    float* A   = f;
    float* B   = f + cn;
    float* Sa  = f + 2 * cn;
    float* Sa2 = f + 3 * cn;
    float* SaP = f + 4 * cn;
    float* SP  = f + 5 * cn;
    float* SP2 = f + 6 * cn;
    float* cry = f + 7 * cn;

    hipMemsetAsync(d_ws, 0, 16, stream);   // zero the double accumulators

    dim3 blk(256);
    dim3 g1((N2 + 255) / 256, C);
    gae_pass1<<<g1, blk, 0, stream>>>(
        (const f2*)rw, (const f2*)vv, (const i2*)dn,
        (f2*)A, (f2*)B, (f2*)Sa, (f2*)Sa2, (f2*)SaP,
        (f2*)SP, (f2*)SP2, (u2*)mask, T, N2);

    if (C <= 64) {
        int wpb = 16;                    // waves (columns) per block
        gae_pass2_ws<<<dim3((N + wpb - 1) / wpb), dim3(wpb * 64), 0, stream>>>(
            A, B, Sa, Sa2, SaP, SP, SP2, cry, sums, N, C);
    } else {
        gae_pass2_seq<<<dim3((N + 63) / 64), dim3(64), 0, stream>>>(
            A, B, Sa, Sa2, SaP, SP, SP2, cry, sums, N, C);
    }

    double M = (double)TN;
    gae_pass3<<<g1, blk, 0, stream>>>(
        (const f2*)rw, (const f2*)vv, (const u2*)mask,
        (const f2*)cry, sums,
        (f2*)d_out, (f2*)((float*)d_out + TN),
        T, N2, 1.0 / M, 1.0 / (M - 1.0));
}